// Round 4
// baseline (2839.803 us; speedup 1.0000x reference)
//
#include <hip/hip_runtime.h>
#include <math.h>

#define T_LEN 16384
#define HDIM 200
#define NPOOL 16

typedef __bf16 v8bf __attribute__((ext_vector_type(8)));
typedef float v4f __attribute__((ext_vector_type(4)));

// ---- scratch in module-scope device globals: d_ws is never touched ----
__device__ float g_ca[T_LEN];
__device__ float g_cb[T_LEN];
__device__ float g_rw2s[NPOOL * HDIM];
__device__ float g_rw2e[NPOOL * HDIM];
__device__ float g_gates[4 * HDIM];
__device__ float g_h[HDIM];
__device__ float g_c[HDIM];
__device__ float g_ch[HDIM];
__device__ float g_cc[HDIM];
__device__ float g_rs[HDIM];
__device__ float g_re[HDIM];
__device__ int   g_ctrl[17];
// bf16 canonical staging (converted from f32 inputs each call)
__device__ __align__(16) unsigned short g_Ubf[T_LEN * 400];        // 13.1 MB
__device__ __align__(16) unsigned short g_w2bf[2][3200 * 416];     // cols 400..415 = 0
__device__ __align__(16) unsigned short g_w3bf[2][3200 * 224];     // cols 200..223 = 0
__device__ __align__(16) unsigned short g_w4bf[2][16 * 416];       // cols 400..415 = 0

__device__ inline unsigned short f2bf(float f) {
    unsigned int u = __builtin_bit_cast(unsigned int, f);
    unsigned int r = u + 0x7FFFu + ((u >> 16) & 1u);
    return (unsigned short)(r >> 16);
}
__device__ inline v8bf zero8() {
    return __builtin_bit_cast(v8bf, make_uint4(0u, 0u, 0u, 0u));
}
__device__ inline int clampT(int v) {
    return v < 0 ? 0 : (v >= T_LEN ? T_LEN - 1 : v);
}

// ---------------- f32 -> bf16 conversions (run once per call) -------------
__global__ void k_cvt_U(const float* __restrict__ src, int n8) {
    int i = blockIdx.x * blockDim.x + threadIdx.x;
    if (i < n8) {
        float4 f0 = reinterpret_cast<const float4*>(src)[i * 2];
        float4 f1 = reinterpret_cast<const float4*>(src)[i * 2 + 1];
        unsigned short o[8] = {f2bf(f0.x), f2bf(f0.y), f2bf(f0.z), f2bf(f0.w),
                               f2bf(f1.x), f2bf(f1.y), f2bf(f1.z), f2bf(f1.w)};
        reinterpret_cast<uint4*>(g_Ubf)[i] = *reinterpret_cast<uint4*>(o);
    }
}

// pad-convert: dst[r][c] = c < ncopy ? bf16(src[r*src_stride+c]) : 0
// dst_stride % 8 == 0, ncopy % 8 == 0 (chunks never straddle).
__global__ void k_cvt_pad(const float* __restrict__ src, unsigned short* __restrict__ dst,
                          int rows, int src_stride, int dst_stride, int ncopy) {
    int cpr = dst_stride >> 3;
    int total = rows * cpr;
    for (int i = blockIdx.x * blockDim.x + threadIdx.x; i < total; i += gridDim.x * blockDim.x) {
        int r = i / cpr, c8 = (i - r * cpr) << 3;
        unsigned short o[8] = {0, 0, 0, 0, 0, 0, 0, 0};
        if (c8 < ncopy) {
            const float* s = src + r * src_stride + c8;
            float4 f0 = reinterpret_cast<const float4*>(s)[0];
            float4 f1 = reinterpret_cast<const float4*>(s)[1];
            o[0] = f2bf(f0.x); o[1] = f2bf(f0.y); o[2] = f2bf(f0.z); o[3] = f2bf(f0.w);
            o[4] = f2bf(f1.x); o[5] = f2bf(f1.y); o[6] = f2bf(f1.z); o[7] = f2bf(f1.w);
        }
        *reinterpret_cast<uint4*>(dst + r * dst_stride + c8) = *reinterpret_cast<uint4*>(o);
    }
}

// ---------------- init: zero LSTM state, ctrl[0] = {0,0,0} ----------------
__global__ void k_init() {
    int t = threadIdx.x;
    if (t < HDIM) { g_h[t] = 0.f; g_c[t] = 0.f; }
    if (t == 0) { g_ctrl[0] = 0; g_ctrl[1] = 0; g_ctrl[2] = 0; }
}

// ---------------- gates = x@Wih.T + h@Whh.T + bih + bhh  (800 rows) -------
__global__ void k_gates(const float* __restrict__ U,
                        const float* __restrict__ Wih,
                        const float* __restrict__ Whh,
                        const float* __restrict__ bih,
                        const float* __restrict__ bhh,
                        int k) {
    int row = blockIdx.x * 16 + (threadIdx.x >> 4);
    int l = threadIdx.x & 15;
    int start = clampT(g_ctrl[k * 3 + 0]), end = clampT(g_ctrl[k * 3 + 1]);
    float sum = 0.f;
    for (int j = l; j < 800; j += 16) {
        float xv = (j < 400) ? U[start * 400 + j] : U[end * 400 + (j - 400)];
        sum += Wih[row * 800 + j] * xv;
    }
    for (int j = l; j < HDIM; j += 16)
        sum += Whh[row * HDIM + j] * g_h[j];
    for (int off = 8; off > 0; off >>= 1) sum += __shfl_xor(sum, off, 16);
    if (l == 0) g_gates[row] = sum + bih[row] + bhh[row];
}

// ---------------- LSTM cell update candidates -----------------------------
__global__ void k_hc() {
    int t = threadIdx.x;
    if (t < HDIM) {
        float gi = g_gates[t], gf = g_gates[HDIM + t];
        float gg = g_gates[2 * HDIM + t], go = g_gates[3 * HDIM + t];
        float si = 1.f / (1.f + expf(-gi));
        float sf = 1.f / (1.f + expf(-gf));
        float so = 1.f / (1.f + expf(-go));
        float tg = tanhf(gg);
        float cn = sf * g_c[t] + si * tg;
        g_cc[t] = cn;
        g_ch[t] = so * tanhf(cn);
    }
}

// ---------------- r = tanh([ch, U[s], U[e]] @ w1.T) for both nets ---------
__global__ void k_r(const float* __restrict__ U,
                    const float* __restrict__ s_w1,
                    const float* __restrict__ e_w1,
                    int k) {
    int g = blockIdx.x * 16 + (threadIdx.x >> 4);
    int l = threadIdx.x & 15;
    int net = g / HDIM, i = g % HDIM;
    const float* w1 = net ? e_w1 : s_w1;
    int start = clampT(g_ctrl[k * 3 + 0]), end = clampT(g_ctrl[k * 3 + 1]);
    float sum = 0.f;
    for (int j = l; j < 1000; j += 16) {
        float cv;
        if (j < 200) cv = g_ch[j];
        else if (j < 600) cv = U[start * 400 + (j - 200)];
        else cv = U[end * 400 + (j - 600)];
        sum += w1[i * 1000 + j] * cv;
    }
    for (int off = 8; off > 0; off >>= 1) sum += __shfl_xor(sum, off, 16);
    if (l == 0) { float* out = net ? g_re : g_rs; out[i] = tanhf(sum); }
}

// ---------------- rw2 = r @ w2[:,400:].T + b2  (3200 each net) ------------
__global__ void k_rw2(const float* __restrict__ s_w2,
                      const float* __restrict__ s_b2,
                      const float* __restrict__ e_w2,
                      const float* __restrict__ e_b2) {
    int g = blockIdx.x * 16 + (threadIdx.x >> 4);
    int l = threadIdx.x & 15;
    int net = g / 3200, n = g % 3200;
    const float* w2 = net ? e_w2 : s_w2;
    const float* b2 = net ? e_b2 : s_b2;
    const float* r = net ? g_re : g_rs;
    float sum = 0.f;
    for (int j = l; j < HDIM; j += 16)
        sum += w2[n * 600 + 400 + j] * r[j];
    for (int off = 8; off > 0; off >>= 1) sum += __shfl_xor(sum, off, 16);
    if (l == 0) { float* out = net ? g_rw2e : g_rw2s; out[n] = sum + b2[n]; }
}

// ---------------- fused HMN: m1 -> m2 -> alpha, row-local per block -------
// grid (256, 2): 64 rows/block, 4 waves x 16 rows. LDS row stride 424:
// phase 1: cols 0..399 = U row (bf16), 400..423 zero. Then cols 0..199
// overwritten with m1, 200..399 with m2; 400..423 stay 0. LDS rows are
// wave-private after the single barrier.
__global__ __launch_bounds__(256) void k_fused(
    const float* __restrict__ b3s, const float* __restrict__ b3e,
    const float* __restrict__ b4s, const float* __restrict__ b4e) {
    const int net = blockIdx.y;
    const unsigned short* w2 = g_w2bf[net];
    const unsigned short* w3 = g_w3bf[net];
    const unsigned short* w4 = g_w4bf[net];
    const float* b3 = net ? b3e : b3s;
    const float* b4 = net ? b4e : b4s;
    const float* rw2 = net ? g_rw2e : g_rw2s;
    float* outv = net ? g_cb : g_ca;
    const int m0 = blockIdx.x * 64;
    __shared__ __align__(16) unsigned short As[64 * 424];
    const int tid = threadIdx.x;
    for (int idx = tid; idx < 64 * 53; idx += 256) {
        int r = idx / 53, chk = idx - r * 53;
        uint4 v = make_uint4(0u, 0u, 0u, 0u);
        if (chk < 50) v = *reinterpret_cast<const uint4*>(g_Ubf + (m0 + r) * 400 + chk * 8);
        *reinterpret_cast<uint4*>(&As[r * 424 + chk * 8]) = v;
    }
    __syncthreads();  // only barrier
    const int lane = tid & 63, wave = tid >> 6;
    const int q = lane >> 4, col = lane & 15;
    const int rowbase = wave * 16;
    const int ar = (rowbase + col) * 424 + q * 8;

    // ---- a1 frags: A[m=col][k], K=416 (cols 400..415 zero) ----
    v8bf a1[13];
#pragma unroll
    for (int ks = 0; ks < 13; ks++)
        a1[ks] = *reinterpret_cast<const v8bf*>(&As[ar + ks * 32]);

    // ---- m1 = maxpool_p(U @ w2a.T + rw2) -> bf16 cols 0..199 ----
    for (int jt = 0; jt < 13; jt++) {
        const int j0 = (jt < 12) ? jt * 16 : 184;
        const int n = j0 + col;
        float mx0 = -INFINITY, mx1 = -INFINITY, mx2 = -INFINITY, mx3 = -INFINITY;
        for (int p = 0; p < NPOOL; p++) {
            v4f acc = {0.f, 0.f, 0.f, 0.f};
            const unsigned short* bp = w2 + (p * HDIM + n) * 416 + q * 8;
#pragma unroll
            for (int ks = 0; ks < 13; ks++) {
                uint4 bu = *reinterpret_cast<const uint4*>(bp + ks * 32);
                acc = __builtin_amdgcn_mfma_f32_16x16x32_bf16(a1[ks], __builtin_bit_cast(v8bf, bu), acc, 0, 0, 0);
            }
            float rv = rw2[p * HDIM + n];
            mx0 = fmaxf(mx0, acc[0] + rv);
            mx1 = fmaxf(mx1, acc[1] + rv);
            mx2 = fmaxf(mx2, acc[2] + rv);
            mx3 = fmaxf(mx3, acc[3] + rv);
        }
        const int rb = (rowbase + q * 4) * 424 + n;
        As[rb + 0 * 424] = f2bf(mx0);
        As[rb + 1 * 424] = f2bf(mx1);
        As[rb + 2 * 424] = f2bf(mx2);
        As[rb + 3 * 424] = f2bf(mx3);
    }

    // ---- a2 frags from m1 (cols 0..199; zero-mask k>=200) ----
    v8bf a2[7];
#pragma unroll
    for (int ks = 0; ks < 7; ks++) {
        if (ks < 6 || q == 0)
            a2[ks] = *reinterpret_cast<const v8bf*>(&As[ar + ks * 32]);
        else
            a2[ks] = zero8();
    }

    // ---- m2 = maxpool_p(m1 @ w3.T + b3) -> bf16 cols 200..399 ----
    for (int jt = 0; jt < 13; jt++) {
        const int j0 = (jt < 12) ? jt * 16 : 184;
        const int n = j0 + col;
        float mx0 = -INFINITY, mx1 = -INFINITY, mx2 = -INFINITY, mx3 = -INFINITY;
        for (int p = 0; p < NPOOL; p++) {
            v4f acc = {0.f, 0.f, 0.f, 0.f};
            const unsigned short* bp = w3 + (p * HDIM + n) * 224 + q * 8;
#pragma unroll
            for (int ks = 0; ks < 7; ks++) {  // w3bf cols 200..223 are zero
                uint4 bu = *reinterpret_cast<const uint4*>(bp + ks * 32);
                acc = __builtin_amdgcn_mfma_f32_16x16x32_bf16(a2[ks], __builtin_bit_cast(v8bf, bu), acc, 0, 0, 0);
            }
            float bv = b3[p * HDIM + n];
            mx0 = fmaxf(mx0, acc[0] + bv);
            mx1 = fmaxf(mx1, acc[1] + bv);
            mx2 = fmaxf(mx2, acc[2] + bv);
            mx3 = fmaxf(mx3, acc[3] + bv);
        }
        const int rb = (rowbase + q * 4) * 424 + 200 + n;
        As[rb + 0 * 424] = f2bf(mx0);
        As[rb + 1 * 424] = f2bf(mx1);
        As[rb + 2 * 424] = f2bf(mx2);
        As[rb + 3 * 424] = f2bf(mx3);
    }

    // ---- alpha = max_n([m1|m2] @ w4.T + b4), K=416 ----
    {
        v4f acc = {0.f, 0.f, 0.f, 0.f};
#pragma unroll
        for (int ks = 0; ks < 13; ks++) {
            v8bf a = *reinterpret_cast<const v8bf*>(&As[ar + ks * 32]);  // 400..415 zero
            uint4 bu = *reinterpret_cast<const uint4*>(w4 + col * 416 + ks * 32 + q * 8);  // pad zero
            acc = __builtin_amdgcn_mfma_f32_16x16x32_bf16(a, __builtin_bit_cast(v8bf, bu), acc, 0, 0, 0);
        }
        float bb = b4[col];
        float v0 = acc[0] + bb, v1 = acc[1] + bb, v2 = acc[2] + bb, v3 = acc[3] + bb;
        for (int off = 1; off < 16; off <<= 1) {
            v0 = fmaxf(v0, __shfl_xor(v0, off, 16));
            v1 = fmaxf(v1, __shfl_xor(v1, off, 16));
            v2 = fmaxf(v2, __shfl_xor(v2, off, 16));
            v3 = fmaxf(v3, __shfl_xor(v3, off, 16));
        }
        if (col == 0) {
            const int tb = m0 + rowbase + q * 4;
            outv[tb + 0] = v0;
            outv[tb + 1] = v1;
            outv[tb + 2] = v2;
            outv[tb + 3] = v3;
        }
    }
}

// ---------------- argmax over T (block 0: ca -> ns, block 1: cb -> ne) ----
__global__ void k_argmax() {
    const float* src = blockIdx.x ? g_cb : g_ca;
    __shared__ float sv[256];
    __shared__ int si[256];
    float best = -INFINITY;
    int bi = T_LEN - 1;
    for (int t = threadIdx.x; t < T_LEN; t += 256) {
        float v = src[t];
        if (v > best) { best = v; bi = t; }
    }
    sv[threadIdx.x] = best; si[threadIdx.x] = bi;
    __syncthreads();
    for (int s = 128; s > 0; s >>= 1) {
        if (threadIdx.x < s) {
            float ov = sv[threadIdx.x + s]; int oi = si[threadIdx.x + s];
            if (ov > sv[threadIdx.x] || (ov == sv[threadIdx.x] && oi < si[threadIdx.x])) {
                sv[threadIdx.x] = ov; si[threadIdx.x] = oi;
            }
        }
        __syncthreads();
    }
    if (threadIdx.x == 0) g_ctrl[15 + blockIdx.x] = clampT(si[0]);
}

// ---------------- commit: freeze-select outputs + state, advance ctrl -----
__global__ void k_commit(int k, float* __restrict__ out) {
    int done = g_ctrl[k * 3 + 2];
    if (blockIdx.x < 128) {
        int is_beta = blockIdx.x >= 64;
        int t = ((int)blockIdx.x & 63) * 256 + threadIdx.x;
        float* row = out + (is_beta ? 4 * T_LEN : 0) + k * T_LEN;
        if (done) row[t] = row[t - T_LEN];
        else row[t] = (is_beta ? g_cb : g_ca)[t];
    } else {
        int t = threadIdx.x;
        if (t < HDIM && !done) { g_h[t] = g_ch[t]; g_c[t] = g_cc[t]; }
        if (t == 0) {
            int sp = g_ctrl[k * 3 + 0], ep = g_ctrl[k * 3 + 1];
            int ns = g_ctrl[15], ne = g_ctrl[16];
            if (done) {
                g_ctrl[(k + 1) * 3 + 0] = sp;
                g_ctrl[(k + 1) * 3 + 1] = ep;
                g_ctrl[(k + 1) * 3 + 2] = 1;
            } else {
                g_ctrl[(k + 1) * 3 + 0] = ns;
                g_ctrl[(k + 1) * 3 + 1] = ne;
                g_ctrl[(k + 1) * 3 + 2] = (k == 0) ? 0 : ((ns == sp && ne == ep) ? 1 : 0);
            }
        }
    }
}

extern "C" void kernel_launch(void* const* d_in, const int* in_sizes, int n_in,
                              void* d_out, int out_size, void* d_ws, size_t ws_size,
                              hipStream_t stream) {
    const float* U    = (const float*)d_in[0];
    const float* Wih  = (const float*)d_in[1];
    const float* Whh  = (const float*)d_in[2];
    const float* bih  = (const float*)d_in[3];
    const float* bhh  = (const float*)d_in[4];
    const float* s_w1 = (const float*)d_in[5];
    const float* s_w2 = (const float*)d_in[6];
    const float* s_b2 = (const float*)d_in[7];
    const float* s_w3 = (const float*)d_in[8];
    const float* s_b3 = (const float*)d_in[9];
    const float* s_w4 = (const float*)d_in[10];
    const float* s_b4 = (const float*)d_in[11];
    const float* e_w1 = (const float*)d_in[12];
    const float* e_w2 = (const float*)d_in[13];
    const float* e_b2 = (const float*)d_in[14];
    const float* e_w3 = (const float*)d_in[15];
    const float* e_b3 = (const float*)d_in[16];
    const float* e_w4 = (const float*)d_in[17];
    const float* e_b4 = (const float*)d_in[18];
    float* out = (float*)d_out;
    (void)d_ws; (void)ws_size; (void)in_sizes; (void)n_in; (void)out_size;

    unsigned short* w2s_d; unsigned short* w2e_d;
    unsigned short* w3s_d; unsigned short* w3e_d;
    unsigned short* w4s_d; unsigned short* w4e_d;
    hipGetSymbolAddress((void**)&w2s_d, HIP_SYMBOL(g_w2bf));  // [0]
    w2e_d = w2s_d + 3200 * 416;
    hipGetSymbolAddress((void**)&w3s_d, HIP_SYMBOL(g_w3bf));
    w3e_d = w3s_d + 3200 * 224;
    hipGetSymbolAddress((void**)&w4s_d, HIP_SYMBOL(g_w4bf));
    w4e_d = w4s_d + 16 * 416;

    // one-time (per call) conversions
    k_cvt_U<<<3200, 256, 0, stream>>>(U, T_LEN * 400 / 8);
    k_cvt_pad<<<650, 256, 0, stream>>>(s_w2, w2s_d, 3200, 600, 416, 400);
    k_cvt_pad<<<650, 256, 0, stream>>>(e_w2, w2e_d, 3200, 600, 416, 400);
    k_cvt_pad<<<350, 256, 0, stream>>>(s_w3, w3s_d, 3200, 200, 224, 200);
    k_cvt_pad<<<350, 256, 0, stream>>>(e_w3, w3e_d, 3200, 200, 224, 200);
    k_cvt_pad<<<4, 256, 0, stream>>>(s_w4, w4s_d, 16, 400, 416, 400);
    k_cvt_pad<<<4, 256, 0, stream>>>(e_w4, w4e_d, 16, 400, 416, 400);

    k_init<<<1, 256, 0, stream>>>();
    for (int k = 0; k < 4; k++) {
        k_gates<<<50, 256, 0, stream>>>(U, Wih, Whh, bih, bhh, k);
        k_hc<<<1, 256, 0, stream>>>();
        k_r<<<25, 256, 0, stream>>>(U, s_w1, e_w1, k);
        k_rw2<<<400, 256, 0, stream>>>(s_w2, s_b2, e_w2, e_b2);
        k_fused<<<dim3(256, 2), 256, 0, stream>>>(s_b3, e_b3, s_b4, e_b4);
        k_argmax<<<2, 256, 0, stream>>>();
        k_commit<<<129, 256, 0, stream>>>(k, out);
    }
}

// Round 5
// 2516.423 us; speedup vs baseline: 1.1285x; 1.1285x over previous
//
#include <hip/hip_runtime.h>
#include <math.h>

#define T_LEN 16384
#define HDIM 200
#define NPOOL 16

typedef __bf16 v8bf __attribute__((ext_vector_type(8)));
typedef float v4f __attribute__((ext_vector_type(4)));

// ---- scratch in module-scope device globals: d_ws is never touched ----
__device__ float g_ca[T_LEN];
__device__ float g_cb[T_LEN];
__device__ float g_rw2s[NPOOL * HDIM];
__device__ float g_rw2e[NPOOL * HDIM];
__device__ float g_gates[4 * HDIM];
__device__ float g_h[HDIM];
__device__ float g_c[HDIM];
__device__ float g_ch[HDIM];
__device__ float g_cc[HDIM];
__device__ float g_rs[HDIM];
__device__ float g_re[HDIM];
__device__ int   g_ctrl[17];
// bf16 canonical staging (converted from f32 inputs each call)
__device__ __align__(16) unsigned short g_Ubf[T_LEN * 400];        // 13.1 MB
__device__ __align__(16) unsigned short g_w2bf[2][3200 * 416];     // cols 400..415 = 0
__device__ __align__(16) unsigned short g_w3bf[2][3200 * 224];     // cols 200..223 = 0
__device__ __align__(16) unsigned short g_w4bf[2][16 * 416];       // cols 400..415 = 0

__device__ inline unsigned short f2bf(float f) {
    unsigned int u = __builtin_bit_cast(unsigned int, f);
    unsigned int r = u + 0x7FFFu + ((u >> 16) & 1u);
    return (unsigned short)(r >> 16);
}
__device__ inline v8bf zero8() {
    return __builtin_bit_cast(v8bf, make_uint4(0u, 0u, 0u, 0u));
}
__device__ inline int clampT(int v) {
    return v < 0 ? 0 : (v >= T_LEN ? T_LEN - 1 : v);
}

// ---------------- f32 -> bf16 conversions (run once per call) -------------
__global__ void k_cvt_U(const float* __restrict__ src, int n8) {
    int i = blockIdx.x * blockDim.x + threadIdx.x;
    if (i < n8) {
        float4 f0 = reinterpret_cast<const float4*>(src)[i * 2];
        float4 f1 = reinterpret_cast<const float4*>(src)[i * 2 + 1];
        unsigned short o[8] = {f2bf(f0.x), f2bf(f0.y), f2bf(f0.z), f2bf(f0.w),
                               f2bf(f1.x), f2bf(f1.y), f2bf(f1.z), f2bf(f1.w)};
        reinterpret_cast<uint4*>(g_Ubf)[i] = *reinterpret_cast<uint4*>(o);
    }
}

// pad-convert: dst[r][c] = c < ncopy ? bf16(src[r*src_stride+c]) : 0
__global__ void k_cvt_pad(const float* __restrict__ src, unsigned short* __restrict__ dst,
                          int rows, int src_stride, int dst_stride, int ncopy) {
    int cpr = dst_stride >> 3;
    int total = rows * cpr;
    for (int i = blockIdx.x * blockDim.x + threadIdx.x; i < total; i += gridDim.x * blockDim.x) {
        int r = i / cpr, c8 = (i - r * cpr) << 3;
        unsigned short o[8] = {0, 0, 0, 0, 0, 0, 0, 0};
        if (c8 < ncopy) {
            const float* s = src + r * src_stride + c8;
            float4 f0 = reinterpret_cast<const float4*>(s)[0];
            float4 f1 = reinterpret_cast<const float4*>(s)[1];
            o[0] = f2bf(f0.x); o[1] = f2bf(f0.y); o[2] = f2bf(f0.z); o[3] = f2bf(f0.w);
            o[4] = f2bf(f1.x); o[5] = f2bf(f1.y); o[6] = f2bf(f1.z); o[7] = f2bf(f1.w);
        }
        *reinterpret_cast<uint4*>(dst + r * dst_stride + c8) = *reinterpret_cast<uint4*>(o);
    }
}

// ---------------- init ----------------------------------------------------
__global__ void k_init() {
    int t = threadIdx.x;
    if (t < HDIM) { g_h[t] = 0.f; g_c[t] = 0.f; }
    if (t == 0) { g_ctrl[0] = 0; g_ctrl[1] = 0; g_ctrl[2] = 0; }
}

// ---------------- gates = x@Wih.T + h@Whh.T + bih + bhh  (800 rows) -------
__global__ void k_gates(const float* __restrict__ U,
                        const float* __restrict__ Wih,
                        const float* __restrict__ Whh,
                        const float* __restrict__ bih,
                        const float* __restrict__ bhh,
                        int k) {
    int row = blockIdx.x * 16 + (threadIdx.x >> 4);
    int l = threadIdx.x & 15;
    int start = clampT(g_ctrl[k * 3 + 0]), end = clampT(g_ctrl[k * 3 + 1]);
    float sum = 0.f;
    for (int j = l; j < 800; j += 16) {
        float xv = (j < 400) ? U[start * 400 + j] : U[end * 400 + (j - 400)];
        sum += Wih[row * 800 + j] * xv;
    }
    for (int j = l; j < HDIM; j += 16)
        sum += Whh[row * HDIM + j] * g_h[j];
    for (int off = 8; off > 0; off >>= 1) sum += __shfl_xor(sum, off, 16);
    if (l == 0) g_gates[row] = sum + bih[row] + bhh[row];
}

// ---------------- LSTM cell update candidates -----------------------------
__global__ void k_hc() {
    int t = threadIdx.x;
    if (t < HDIM) {
        float gi = g_gates[t], gf = g_gates[HDIM + t];
        float gg = g_gates[2 * HDIM + t], go = g_gates[3 * HDIM + t];
        float si = 1.f / (1.f + expf(-gi));
        float sf = 1.f / (1.f + expf(-gf));
        float so = 1.f / (1.f + expf(-go));
        float tg = tanhf(gg);
        float cn = sf * g_c[t] + si * tg;
        g_cc[t] = cn;
        g_ch[t] = so * tanhf(cn);
    }
}

// ---------------- r = tanh([ch, U[s], U[e]] @ w1.T) for both nets ---------
__global__ void k_r(const float* __restrict__ U,
                    const float* __restrict__ s_w1,
                    const float* __restrict__ e_w1,
                    int k) {
    int g = blockIdx.x * 16 + (threadIdx.x >> 4);
    int l = threadIdx.x & 15;
    int net = g / HDIM, i = g % HDIM;
    const float* w1 = net ? e_w1 : s_w1;
    int start = clampT(g_ctrl[k * 3 + 0]), end = clampT(g_ctrl[k * 3 + 1]);
    float sum = 0.f;
    for (int j = l; j < 1000; j += 16) {
        float cv;
        if (j < 200) cv = g_ch[j];
        else if (j < 600) cv = U[start * 400 + (j - 200)];
        else cv = U[end * 400 + (j - 600)];
        sum += w1[i * 1000 + j] * cv;
    }
    for (int off = 8; off > 0; off >>= 1) sum += __shfl_xor(sum, off, 16);
    if (l == 0) { float* out = net ? g_re : g_rs; out[i] = tanhf(sum); }
}

// ---------------- rw2 = r @ w2[:,400:].T + b2  (3200 each net) ------------
__global__ void k_rw2(const float* __restrict__ s_w2,
                      const float* __restrict__ s_b2,
                      const float* __restrict__ e_w2,
                      const float* __restrict__ e_b2) {
    int g = blockIdx.x * 16 + (threadIdx.x >> 4);
    int l = threadIdx.x & 15;
    int net = g / 3200, n = g % 3200;
    const float* w2 = net ? e_w2 : s_w2;
    const float* b2 = net ? e_b2 : s_b2;
    const float* r = net ? g_re : g_rs;
    float sum = 0.f;
    for (int j = l; j < HDIM; j += 16)
        sum += w2[n * 600 + 400 + j] * r[j];
    for (int off = 8; off > 0; off >>= 1) sum += __shfl_xor(sum, off, 16);
    if (l == 0) { float* out = net ? g_rw2e : g_rw2s; out[n] = sum + b2[n]; }
}

// ---------------- fused HMN: m1 -> m2 -> alpha, row-local per block -------
// grid (256, 2), block 256 (4 waves x 16 rows), __launch_bounds__(256,2):
// 2 waves/SIMD target -> ~256 VGPR budget so the 13x2 B-fragment double
// buffer lives in registers (R4: VGPR=68 serialized every B load at L2
// latency -> MfmaUtil 9%; this is the fix).
__global__ __launch_bounds__(256, 2) void k_fused(
    const float* __restrict__ b3s, const float* __restrict__ b3e,
    const float* __restrict__ b4s, const float* __restrict__ b4e) {
    const int net = blockIdx.y;
    const unsigned short* w2 = g_w2bf[net];
    const unsigned short* w3 = g_w3bf[net];
    const unsigned short* w4 = g_w4bf[net];
    const float* b3 = net ? b3e : b3s;
    const float* b4 = net ? b4e : b4s;
    const float* rw2 = net ? g_rw2e : g_rw2s;
    float* outv = net ? g_cb : g_ca;
    const int m0 = blockIdx.x * 64;
    __shared__ __align__(16) unsigned short As[64 * 424];
    const int tid = threadIdx.x;
    for (int idx = tid; idx < 64 * 53; idx += 256) {
        int r = idx / 53, chk = idx - r * 53;
        uint4 v = make_uint4(0u, 0u, 0u, 0u);
        if (chk < 50) v = *reinterpret_cast<const uint4*>(g_Ubf + (m0 + r) * 400 + chk * 8);
        *reinterpret_cast<uint4*>(&As[r * 424 + chk * 8]) = v;
    }
    __syncthreads();  // only barrier
    const int lane = tid & 63, wave = tid >> 6;
    const int q = lane >> 4, col = lane & 15;
    const int rowbase = wave * 16;
    const int ar = (rowbase + col) * 424 + q * 8;

    // ---- a1 frags: A[m=col][k], K=416 (cols 400..415 zero) ----
    v8bf a1[13];
#pragma unroll
    for (int ks = 0; ks < 13; ks++)
        a1[ks] = *reinterpret_cast<const v8bf*>(&As[ar + ks * 32]);

    // ---- m1 = maxpool_p(U @ w2a.T + rw2) -> bf16 cols 0..199 ----
    for (int jt = 0; jt < 13; jt++) {
        const int j0 = (jt < 12) ? jt * 16 : 184;
        const int n = j0 + col;
        const unsigned short* wbase = w2 + n * 416 + q * 8;
        v8bf b0[13], b1[13];
#pragma unroll
        for (int ks = 0; ks < 13; ks++)
            b0[ks] = *reinterpret_cast<const v8bf*>(wbase + ks * 32);
        float mx0 = -INFINITY, mx1 = -INFINITY, mx2 = -INFINITY, mx3 = -INFINITY;
#pragma unroll 1
        for (int p = 0; p < NPOOL; p += 2) {
            // prefetch p+1 while computing p
            {
                const unsigned short* wp = wbase + (p + 1) * (HDIM * 416);
#pragma unroll
                for (int ks = 0; ks < 13; ks++)
                    b1[ks] = *reinterpret_cast<const v8bf*>(wp + ks * 32);
            }
            {
                v4f acc0 = {0.f, 0.f, 0.f, 0.f}, acc1 = {0.f, 0.f, 0.f, 0.f};
#pragma unroll
                for (int ks = 0; ks < 12; ks += 2) {
                    acc0 = __builtin_amdgcn_mfma_f32_16x16x32_bf16(a1[ks], b0[ks], acc0, 0, 0, 0);
                    acc1 = __builtin_amdgcn_mfma_f32_16x16x32_bf16(a1[ks + 1], b0[ks + 1], acc1, 0, 0, 0);
                }
                acc0 = __builtin_amdgcn_mfma_f32_16x16x32_bf16(a1[12], b0[12], acc0, 0, 0, 0);
                float rv = rw2[p * HDIM + n];
                mx0 = fmaxf(mx0, acc0[0] + acc1[0] + rv);
                mx1 = fmaxf(mx1, acc0[1] + acc1[1] + rv);
                mx2 = fmaxf(mx2, acc0[2] + acc1[2] + rv);
                mx3 = fmaxf(mx3, acc0[3] + acc1[3] + rv);
            }
            // prefetch p+2 while computing p+1
            if (p + 2 < NPOOL) {
                const unsigned short* wp = wbase + (p + 2) * (HDIM * 416);
#pragma unroll
                for (int ks = 0; ks < 13; ks++)
                    b0[ks] = *reinterpret_cast<const v8bf*>(wp + ks * 32);
            }
            {
                v4f acc0 = {0.f, 0.f, 0.f, 0.f}, acc1 = {0.f, 0.f, 0.f, 0.f};
#pragma unroll
                for (int ks = 0; ks < 12; ks += 2) {
                    acc0 = __builtin_amdgcn_mfma_f32_16x16x32_bf16(a1[ks], b1[ks], acc0, 0, 0, 0);
                    acc1 = __builtin_amdgcn_mfma_f32_16x16x32_bf16(a1[ks + 1], b1[ks + 1], acc1, 0, 0, 0);
                }
                acc0 = __builtin_amdgcn_mfma_f32_16x16x32_bf16(a1[12], b1[12], acc0, 0, 0, 0);
                float rv = rw2[(p + 1) * HDIM + n];
                mx0 = fmaxf(mx0, acc0[0] + acc1[0] + rv);
                mx1 = fmaxf(mx1, acc0[1] + acc1[1] + rv);
                mx2 = fmaxf(mx2, acc0[2] + acc1[2] + rv);
                mx3 = fmaxf(mx3, acc0[3] + acc1[3] + rv);
            }
        }
        const int rb = (rowbase + q * 4) * 424 + n;
        As[rb + 0 * 424] = f2bf(mx0);
        As[rb + 1 * 424] = f2bf(mx1);
        As[rb + 2 * 424] = f2bf(mx2);
        As[rb + 3 * 424] = f2bf(mx3);
    }

    // ---- a2 frags from m1 (cols 0..199; zero-mask k>=200) ----
    v8bf a2[7];
#pragma unroll
    for (int ks = 0; ks < 7; ks++) {
        if (ks < 6 || q == 0)
            a2[ks] = *reinterpret_cast<const v8bf*>(&As[ar + ks * 32]);
        else
            a2[ks] = zero8();
    }

    // ---- m2 = maxpool_p(m1 @ w3.T + b3) -> bf16 cols 200..399 ----
    for (int jt = 0; jt < 13; jt++) {
        const int j0 = (jt < 12) ? jt * 16 : 184;
        const int n = j0 + col;
        const unsigned short* wbase = w3 + n * 224 + q * 8;
        v8bf c0[7], c1[7];
#pragma unroll
        for (int ks = 0; ks < 7; ks++)
            c0[ks] = *reinterpret_cast<const v8bf*>(wbase + ks * 32);
        float mx0 = -INFINITY, mx1 = -INFINITY, mx2 = -INFINITY, mx3 = -INFINITY;
#pragma unroll 1
        for (int p = 0; p < NPOOL; p += 2) {
            {
                const unsigned short* wp = wbase + (p + 1) * (HDIM * 224);
#pragma unroll
                for (int ks = 0; ks < 7; ks++)
                    c1[ks] = *reinterpret_cast<const v8bf*>(wp + ks * 32);
            }
            {
                v4f acc0 = {0.f, 0.f, 0.f, 0.f}, acc1 = {0.f, 0.f, 0.f, 0.f};
#pragma unroll
                for (int ks = 0; ks < 6; ks += 2) {
                    acc0 = __builtin_amdgcn_mfma_f32_16x16x32_bf16(a2[ks], c0[ks], acc0, 0, 0, 0);
                    acc1 = __builtin_amdgcn_mfma_f32_16x16x32_bf16(a2[ks + 1], c0[ks + 1], acc1, 0, 0, 0);
                }
                acc0 = __builtin_amdgcn_mfma_f32_16x16x32_bf16(a2[6], c0[6], acc0, 0, 0, 0);
                float bv = b3[p * HDIM + n];
                mx0 = fmaxf(mx0, acc0[0] + acc1[0] + bv);
                mx1 = fmaxf(mx1, acc0[1] + acc1[1] + bv);
                mx2 = fmaxf(mx2, acc0[2] + acc1[2] + bv);
                mx3 = fmaxf(mx3, acc0[3] + acc1[3] + bv);
            }
            if (p + 2 < NPOOL) {
                const unsigned short* wp = wbase + (p + 2) * (HDIM * 224);
#pragma unroll
                for (int ks = 0; ks < 7; ks++)
                    c0[ks] = *reinterpret_cast<const v8bf*>(wp + ks * 32);
            }
            {
                v4f acc0 = {0.f, 0.f, 0.f, 0.f}, acc1 = {0.f, 0.f, 0.f, 0.f};
#pragma unroll
                for (int ks = 0; ks < 6; ks += 2) {
                    acc0 = __builtin_amdgcn_mfma_f32_16x16x32_bf16(a2[ks], c1[ks], acc0, 0, 0, 0);
                    acc1 = __builtin_amdgcn_mfma_f32_16x16x32_bf16(a2[ks + 1], c1[ks + 1], acc1, 0, 0, 0);
                }
                acc0 = __builtin_amdgcn_mfma_f32_16x16x32_bf16(a2[6], c1[6], acc0, 0, 0, 0);
                float bv = b3[(p + 1) * HDIM + n];
                mx0 = fmaxf(mx0, acc0[0] + acc1[0] + bv);
                mx1 = fmaxf(mx1, acc0[1] + acc1[1] + bv);
                mx2 = fmaxf(mx2, acc0[2] + acc1[2] + bv);
                mx3 = fmaxf(mx3, acc0[3] + acc1[3] + bv);
            }
        }
        const int rb = (rowbase + q * 4) * 424 + 200 + n;
        As[rb + 0 * 424] = f2bf(mx0);
        As[rb + 1 * 424] = f2bf(mx1);
        As[rb + 2 * 424] = f2bf(mx2);
        As[rb + 3 * 424] = f2bf(mx3);
    }

    // ---- alpha = max_n([m1|m2] @ w4.T + b4), K=416 ----
    {
        v4f acc = {0.f, 0.f, 0.f, 0.f};
#pragma unroll
        for (int ks = 0; ks < 13; ks++) {
            v8bf a = *reinterpret_cast<const v8bf*>(&As[ar + ks * 32]);  // 400..415 zero
            uint4 bu = *reinterpret_cast<const uint4*>(w4 + col * 416 + ks * 32 + q * 8);  // pad zero
            acc = __builtin_amdgcn_mfma_f32_16x16x32_bf16(a, __builtin_bit_cast(v8bf, bu), acc, 0, 0, 0);
        }
        float bb = b4[col];
        float v0 = acc[0] + bb, v1 = acc[1] + bb, v2 = acc[2] + bb, v3 = acc[3] + bb;
        for (int off = 1; off < 16; off <<= 1) {
            v0 = fmaxf(v0, __shfl_xor(v0, off, 16));
            v1 = fmaxf(v1, __shfl_xor(v1, off, 16));
            v2 = fmaxf(v2, __shfl_xor(v2, off, 16));
            v3 = fmaxf(v3, __shfl_xor(v3, off, 16));
        }
        if (col == 0) {
            const int tb = m0 + rowbase + q * 4;
            outv[tb + 0] = v0;
            outv[tb + 1] = v1;
            outv[tb + 2] = v2;
            outv[tb + 3] = v3;
        }
    }
}

// ---------------- argmax over T (block 0: ca -> ns, block 1: cb -> ne) ----
__global__ void k_argmax() {
    const float* src = blockIdx.x ? g_cb : g_ca;
    __shared__ float sv[256];
    __shared__ int si[256];
    float best = -INFINITY;
    int bi = T_LEN - 1;
    for (int t = threadIdx.x; t < T_LEN; t += 256) {
        float v = src[t];
        if (v > best) { best = v; bi = t; }
    }
    sv[threadIdx.x] = best; si[threadIdx.x] = bi;
    __syncthreads();
    for (int s = 128; s > 0; s >>= 1) {
        if (threadIdx.x < s) {
            float ov = sv[threadIdx.x + s]; int oi = si[threadIdx.x + s];
            if (ov > sv[threadIdx.x] || (ov == sv[threadIdx.x] && oi < si[threadIdx.x])) {
                sv[threadIdx.x] = ov; si[threadIdx.x] = oi;
            }
        }
        __syncthreads();
    }
    if (threadIdx.x == 0) g_ctrl[15 + blockIdx.x] = clampT(si[0]);
}

// ---------------- commit: freeze-select outputs + state, advance ctrl -----
__global__ void k_commit(int k, float* __restrict__ out) {
    int done = g_ctrl[k * 3 + 2];
    if (blockIdx.x < 128) {
        int is_beta = blockIdx.x >= 64;
        int t = ((int)blockIdx.x & 63) * 256 + threadIdx.x;
        float* row = out + (is_beta ? 4 * T_LEN : 0) + k * T_LEN;
        if (done) row[t] = row[t - T_LEN];
        else row[t] = (is_beta ? g_cb : g_ca)[t];
    } else {
        int t = threadIdx.x;
        if (t < HDIM && !done) { g_h[t] = g_ch[t]; g_c[t] = g_cc[t]; }
        if (t == 0) {
            int sp = g_ctrl[k * 3 + 0], ep = g_ctrl[k * 3 + 1];
            int ns = g_ctrl[15], ne = g_ctrl[16];
            if (done) {
                g_ctrl[(k + 1) * 3 + 0] = sp;
                g_ctrl[(k + 1) * 3 + 1] = ep;
                g_ctrl[(k + 1) * 3 + 2] = 1;
            } else {
                g_ctrl[(k + 1) * 3 + 0] = ns;
                g_ctrl[(k + 1) * 3 + 1] = ne;
                g_ctrl[(k + 1) * 3 + 2] = (k == 0) ? 0 : ((ns == sp && ne == ep) ? 1 : 0);
            }
        }
    }
}

extern "C" void kernel_launch(void* const* d_in, const int* in_sizes, int n_in,
                              void* d_out, int out_size, void* d_ws, size_t ws_size,
                              hipStream_t stream) {
    const float* U    = (const float*)d_in[0];
    const float* Wih  = (const float*)d_in[1];
    const float* Whh  = (const float*)d_in[2];
    const float* bih  = (const float*)d_in[3];
    const float* bhh  = (const float*)d_in[4];
    const float* s_w1 = (const float*)d_in[5];
    const float* s_w2 = (const float*)d_in[6];
    const float* s_b2 = (const float*)d_in[7];
    const float* s_w3 = (const float*)d_in[8];
    const float* s_b3 = (const float*)d_in[9];
    const float* s_w4 = (const float*)d_in[10];
    const float* s_b4 = (const float*)d_in[11];
    const float* e_w1 = (const float*)d_in[12];
    const float* e_w2 = (const float*)d_in[13];
    const float* e_b2 = (const float*)d_in[14];
    const float* e_w3 = (const float*)d_in[15];
    const float* e_b3 = (const float*)d_in[16];
    const float* e_w4 = (const float*)d_in[17];
    const float* e_b4 = (const float*)d_in[18];
    float* out = (float*)d_out;
    (void)d_ws; (void)ws_size; (void)in_sizes; (void)n_in; (void)out_size;

    unsigned short* w2s_d; unsigned short* w2e_d;
    unsigned short* w3s_d; unsigned short* w3e_d;
    unsigned short* w4s_d; unsigned short* w4e_d;
    hipGetSymbolAddress((void**)&w2s_d, HIP_SYMBOL(g_w2bf));  // [0]
    w2e_d = w2s_d + 3200 * 416;
    hipGetSymbolAddress((void**)&w3s_d, HIP_SYMBOL(g_w3bf));
    w3e_d = w3s_d + 3200 * 224;
    hipGetSymbolAddress((void**)&w4s_d, HIP_SYMBOL(g_w4bf));
    w4e_d = w4s_d + 16 * 416;

    // one-time (per call) conversions
    k_cvt_U<<<3200, 256, 0, stream>>>(U, T_LEN * 400 / 8);
    k_cvt_pad<<<650, 256, 0, stream>>>(s_w2, w2s_d, 3200, 600, 416, 400);
    k_cvt_pad<<<650, 256, 0, stream>>>(e_w2, w2e_d, 3200, 600, 416, 400);
    k_cvt_pad<<<350, 256, 0, stream>>>(s_w3, w3s_d, 3200, 200, 224, 200);
    k_cvt_pad<<<350, 256, 0, stream>>>(e_w3, w3e_d, 3200, 200, 224, 200);
    k_cvt_pad<<<4, 256, 0, stream>>>(s_w4, w4s_d, 16, 400, 416, 400);
    k_cvt_pad<<<4, 256, 0, stream>>>(e_w4, w4e_d, 16, 400, 416, 400);

    k_init<<<1, 256, 0, stream>>>();
    for (int k = 0; k < 4; k++) {
        k_gates<<<50, 256, 0, stream>>>(U, Wih, Whh, bih, bhh, k);
        k_hc<<<1, 256, 0, stream>>>();
        k_r<<<25, 256, 0, stream>>>(U, s_w1, e_w1, k);
        k_rw2<<<400, 256, 0, stream>>>(s_w2, s_b2, e_w2, e_b2);
        k_fused<<<dim3(256, 2), 256, 0, stream>>>(s_b3, e_b3, s_b4, e_b4);
        k_argmax<<<2, 256, 0, stream>>>();
        k_commit<<<129, 256, 0, stream>>>(k, out);
    }
}

// Round 6
// 2491.581 us; speedup vs baseline: 1.1398x; 1.0100x over previous
//
#include <hip/hip_runtime.h>
#include <math.h>

#define T_LEN 16384
#define HDIM 200
#define NPOOL 16

typedef __bf16 v8bf __attribute__((ext_vector_type(8)));
typedef float v4f __attribute__((ext_vector_type(4)));

// ---- scratch in module-scope device globals: d_ws is never touched ----
__device__ float g_ca[T_LEN];
__device__ float g_cb[T_LEN];
__device__ float g_rw2s[NPOOL * HDIM];
__device__ float g_rw2e[NPOOL * HDIM];
__device__ float g_gates[4 * HDIM];
__device__ float g_h[HDIM];
__device__ float g_c[HDIM];
__device__ float g_ch[HDIM];
__device__ float g_cc[HDIM];
__device__ float g_rs[HDIM];
__device__ float g_re[HDIM];
__device__ int   g_ctrl[17];
// bf16 canonical staging (converted from f32 inputs each call)
__device__ __align__(16) unsigned short g_Ubf[T_LEN * 400];        // 13.1 MB
__device__ __align__(16) unsigned short g_w2bf[2][3200 * 416];     // cols 400..415 = 0
__device__ __align__(16) unsigned short g_w3bf[2][3200 * 224];     // cols 200..223 = 0
__device__ __align__(16) unsigned short g_w4a[2][16 * 456];        // alpha layout: [0..199]=w4[:,0:200], [200..223]=0, [224..423]=w4[:,200:400], [424..455]=0

__device__ inline unsigned short f2bf(float f) {
    unsigned int u = __builtin_bit_cast(unsigned int, f);
    unsigned int r = u + 0x7FFFu + ((u >> 16) & 1u);
    return (unsigned short)(r >> 16);
}
__device__ inline int clampT(int v) {
    return v < 0 ? 0 : (v >= T_LEN ? T_LEN - 1 : v);
}

// ---------------- f32 -> bf16 conversions (run once per call) -------------
__global__ void k_cvt_U(const float* __restrict__ src, int n8) {
    int i = blockIdx.x * blockDim.x + threadIdx.x;
    if (i < n8) {
        float4 f0 = reinterpret_cast<const float4*>(src)[i * 2];
        float4 f1 = reinterpret_cast<const float4*>(src)[i * 2 + 1];
        unsigned short o[8] = {f2bf(f0.x), f2bf(f0.y), f2bf(f0.z), f2bf(f0.w),
                               f2bf(f1.x), f2bf(f1.y), f2bf(f1.z), f2bf(f1.w)};
        reinterpret_cast<uint4*>(g_Ubf)[i] = *reinterpret_cast<uint4*>(o);
    }
}

__global__ void k_cvt_pad(const float* __restrict__ src, unsigned short* __restrict__ dst,
                          int rows, int src_stride, int dst_stride, int ncopy) {
    int cpr = dst_stride >> 3;
    int total = rows * cpr;
    for (int i = blockIdx.x * blockDim.x + threadIdx.x; i < total; i += gridDim.x * blockDim.x) {
        int r = i / cpr, c8 = (i - r * cpr) << 3;
        unsigned short o[8] = {0, 0, 0, 0, 0, 0, 0, 0};
        if (c8 < ncopy) {
            const float* s = src + r * src_stride + c8;
            float4 f0 = reinterpret_cast<const float4*>(s)[0];
            float4 f1 = reinterpret_cast<const float4*>(s)[1];
            o[0] = f2bf(f0.x); o[1] = f2bf(f0.y); o[2] = f2bf(f0.z); o[3] = f2bf(f0.w);
            o[4] = f2bf(f1.x); o[5] = f2bf(f1.y); o[6] = f2bf(f1.z); o[7] = f2bf(f1.w);
        }
        *reinterpret_cast<uint4*>(dst + r * dst_stride + c8) = *reinterpret_cast<uint4*>(o);
    }
}

// w4 alpha-layout conversion (2 nets x 16 rows x 456 cols)
__global__ void k_cvt_w4(const float* __restrict__ s_w4, const float* __restrict__ e_w4) {
    int i = blockIdx.x * blockDim.x + threadIdx.x;
    if (i >= 2 * 16 * 456) return;
    int net = i / (16 * 456);
    int rem = i - net * (16 * 456);
    int r = rem / 456, k = rem - r * 456;
    const float* src = net ? e_w4 : s_w4;
    float v = 0.f;
    if (k < 200) v = src[r * 400 + k];
    else if (k >= 224 && k < 424) v = src[r * 400 + (k - 24)];
    g_w4a[net][r * 456 + k] = f2bf(v);
}

// ---------------- init ----------------------------------------------------
__global__ void k_init() {
    int t = threadIdx.x;
    if (t < HDIM) { g_h[t] = 0.f; g_c[t] = 0.f; }
    if (t == 0) { g_ctrl[0] = 0; g_ctrl[1] = 0; g_ctrl[2] = 0; }
}

// ---------------- gates = x@Wih.T + h@Whh.T + bih + bhh  (800 rows) -------
__global__ void k_gates(const float* __restrict__ U,
                        const float* __restrict__ Wih,
                        const float* __restrict__ Whh,
                        const float* __restrict__ bih,
                        const float* __restrict__ bhh,
                        int k) {
    int row = blockIdx.x * 16 + (threadIdx.x >> 4);
    int l = threadIdx.x & 15;
    int start = clampT(g_ctrl[k * 3 + 0]), end = clampT(g_ctrl[k * 3 + 1]);
    float sum = 0.f;
    for (int j = l; j < 800; j += 16) {
        float xv = (j < 400) ? U[start * 400 + j] : U[end * 400 + (j - 400)];
        sum += Wih[row * 800 + j] * xv;
    }
    for (int j = l; j < HDIM; j += 16)
        sum += Whh[row * HDIM + j] * g_h[j];
    for (int off = 8; off > 0; off >>= 1) sum += __shfl_xor(sum, off, 16);
    if (l == 0) g_gates[row] = sum + bih[row] + bhh[row];
}

// ---------------- LSTM cell update candidates -----------------------------
__global__ void k_hc() {
    int t = threadIdx.x;
    if (t < HDIM) {
        float gi = g_gates[t], gf = g_gates[HDIM + t];
        float gg = g_gates[2 * HDIM + t], go = g_gates[3 * HDIM + t];
        float si = 1.f / (1.f + expf(-gi));
        float sf = 1.f / (1.f + expf(-gf));
        float so = 1.f / (1.f + expf(-go));
        float tg = tanhf(gg);
        float cn = sf * g_c[t] + si * tg;
        g_cc[t] = cn;
        g_ch[t] = so * tanhf(cn);
    }
}

// ---------------- r = tanh([ch, U[s], U[e]] @ w1.T) for both nets ---------
__global__ void k_r(const float* __restrict__ U,
                    const float* __restrict__ s_w1,
                    const float* __restrict__ e_w1,
                    int k) {
    int g = blockIdx.x * 16 + (threadIdx.x >> 4);
    int l = threadIdx.x & 15;
    int net = g / HDIM, i = g % HDIM;
    const float* w1 = net ? e_w1 : s_w1;
    int start = clampT(g_ctrl[k * 3 + 0]), end = clampT(g_ctrl[k * 3 + 1]);
    float sum = 0.f;
    for (int j = l; j < 1000; j += 16) {
        float cv;
        if (j < 200) cv = g_ch[j];
        else if (j < 600) cv = U[start * 400 + (j - 200)];
        else cv = U[end * 400 + (j - 600)];
        sum += w1[i * 1000 + j] * cv;
    }
    for (int off = 8; off > 0; off >>= 1) sum += __shfl_xor(sum, off, 16);
    if (l == 0) { float* out = net ? g_re : g_rs; out[i] = tanhf(sum); }
}

// ---------------- rw2 = r @ w2[:,400:].T + b2  (3200 each net) ------------
__global__ void k_rw2(const float* __restrict__ s_w2,
                      const float* __restrict__ s_b2,
                      const float* __restrict__ e_w2,
                      const float* __restrict__ e_b2) {
    int g = blockIdx.x * 16 + (threadIdx.x >> 4);
    int l = threadIdx.x & 15;
    int net = g / 3200, n = g % 3200;
    const float* w2 = net ? e_w2 : s_w2;
    const float* b2 = net ? e_b2 : s_b2;
    const float* r = net ? g_re : g_rs;
    float sum = 0.f;
    for (int j = l; j < HDIM; j += 16)
        sum += w2[n * 600 + 400 + j] * r[j];
    for (int off = 8; off > 0; off >>= 1) sum += __shfl_xor(sum, off, 16);
    if (l == 0) { float* out = net ? g_rw2e : g_rw2s; out[n] = sum + b2[n]; }
}

// ---------------- fused HMN, k-outer / p-accumulator-blocked --------------
// grid (256, 2), block 256 = 4 waves. Block owns 64 rows; each WAVE owns all
// 64 rows (4 A-sets) and jt-tiles {wave, wave+4, ...} of the 13 n-tiles.
// Per k-step: 4 LDS A-reads + 8 B-loads feed 32 MFMAs (acc[8 p][4 sets] held
// across K) -> load latency hidden by compute, B traffic /4 vs round 5.
// LDS: As=U (64x424, cols 400..423 zero), Outs (64x456: m1 in 0..199,
// zeros 200..223, m2 in 224..423, zeros 424..455) = 112.6 KB -> 1 block/CU.
__global__ __launch_bounds__(256, 1) void k_fused(
    const float* __restrict__ b3s, const float* __restrict__ b3e,
    const float* __restrict__ b4s, const float* __restrict__ b4e) {
    const int net = blockIdx.y;
    const unsigned short* w2 = g_w2bf[net];
    const unsigned short* w3 = g_w3bf[net];
    const unsigned short* w4 = g_w4a[net];
    const float* b3 = net ? b3e : b3s;
    const float* b4 = net ? b4e : b4s;
    const float* rw2 = net ? g_rw2e : g_rw2s;
    float* outv = net ? g_cb : g_ca;
    const int m0 = blockIdx.x * 64;
    __shared__ __align__(16) unsigned short As[64 * 424];
    __shared__ __align__(16) unsigned short Outs[64 * 456];
    const int tid = threadIdx.x;
    // zero Outs
    for (int idx = tid; idx < 64 * 57; idx += 256) {
        int r = idx / 57, c8 = idx - r * 57;
        *reinterpret_cast<uint4*>(&Outs[r * 456 + c8 * 8]) = make_uint4(0u, 0u, 0u, 0u);
    }
    // stage U rows (cols 400..423 zero)
    for (int idx = tid; idx < 64 * 53; idx += 256) {
        int r = idx / 53, chk = idx - r * 53;
        uint4 v = make_uint4(0u, 0u, 0u, 0u);
        if (chk < 50) v = *reinterpret_cast<const uint4*>(g_Ubf + (m0 + r) * 400 + chk * 8);
        *reinterpret_cast<uint4*>(&As[r * 424 + chk * 8]) = v;
    }
    __syncthreads();
    const int lane = tid & 63, wave = tid >> 6;
    const int q = lane >> 4, col = lane & 15;
    const int qo = q * 8;

    // ================= m1: Outs[0..199] = maxpool_p(U @ w2a.T + rw2) ======
    for (int jt = wave; jt < 13; jt += 4) {
        const int j0 = (jt < 12) ? jt * 16 : 184;
        const int n = j0 + col;
        float mx[4][4];
#pragma unroll
        for (int s = 0; s < 4; s++)
#pragma unroll
            for (int i = 0; i < 4; i++) mx[s][i] = -INFINITY;
#pragma unroll 1
        for (int half = 0; half < 2; half++) {
            v4f acc[8][4];
#pragma unroll
            for (int p8 = 0; p8 < 8; p8++)
#pragma unroll
                for (int s = 0; s < 4; s++) acc[p8][s] = (v4f){0.f, 0.f, 0.f, 0.f};
            const unsigned short* wb = w2 + ((half * 8) * HDIM + n) * 416 + qo;
#pragma unroll 1
            for (int ks = 0; ks < 13; ks++) {
                v8bf a[4];
#pragma unroll
                for (int s = 0; s < 4; s++)
                    a[s] = *reinterpret_cast<const v8bf*>(&As[(s * 16 + col) * 424 + ks * 32 + qo]);
                v8bf b[8];
#pragma unroll
                for (int p8 = 0; p8 < 8; p8++)
                    b[p8] = *reinterpret_cast<const v8bf*>(wb + p8 * (HDIM * 416) + ks * 32);
#pragma unroll
                for (int p8 = 0; p8 < 8; p8++)
#pragma unroll
                    for (int s = 0; s < 4; s++)
                        acc[p8][s] = __builtin_amdgcn_mfma_f32_16x16x32_bf16(a[s], b[p8], acc[p8][s], 0, 0, 0);
            }
#pragma unroll
            for (int p8 = 0; p8 < 8; p8++) {
                float rv = rw2[(half * 8 + p8) * HDIM + n];
#pragma unroll
                for (int s = 0; s < 4; s++)
#pragma unroll
                    for (int i = 0; i < 4; i++)
                        mx[s][i] = fmaxf(mx[s][i], acc[p8][s][i] + rv);
            }
        }
#pragma unroll
        for (int s = 0; s < 4; s++)
#pragma unroll
            for (int i = 0; i < 4; i++)
                Outs[(s * 16 + q * 4 + i) * 456 + n] = f2bf(mx[s][i]);
    }
    __syncthreads();

    // ================= m2: Outs[224..423] = maxpool_p(m1 @ w3.T + b3) =====
    for (int jt = wave; jt < 13; jt += 4) {
        const int j0 = (jt < 12) ? jt * 16 : 184;
        const int n = j0 + col;
        float mx[4][4];
#pragma unroll
        for (int s = 0; s < 4; s++)
#pragma unroll
            for (int i = 0; i < 4; i++) mx[s][i] = -INFINITY;
#pragma unroll 1
        for (int half = 0; half < 2; half++) {
            v4f acc[8][4];
#pragma unroll
            for (int p8 = 0; p8 < 8; p8++)
#pragma unroll
                for (int s = 0; s < 4; s++) acc[p8][s] = (v4f){0.f, 0.f, 0.f, 0.f};
            const unsigned short* wb = w3 + ((half * 8) * HDIM + n) * 224 + qo;
#pragma unroll 1
            for (int ks = 0; ks < 7; ks++) {  // cols 200..223 of Outs & w3bf are zero
                v8bf a[4];
#pragma unroll
                for (int s = 0; s < 4; s++)
                    a[s] = *reinterpret_cast<const v8bf*>(&Outs[(s * 16 + col) * 456 + ks * 32 + qo]);
                v8bf b[8];
#pragma unroll
                for (int p8 = 0; p8 < 8; p8++)
                    b[p8] = *reinterpret_cast<const v8bf*>(wb + p8 * (HDIM * 224) + ks * 32);
#pragma unroll
                for (int p8 = 0; p8 < 8; p8++)
#pragma unroll
                    for (int s = 0; s < 4; s++)
                        acc[p8][s] = __builtin_amdgcn_mfma_f32_16x16x32_bf16(a[s], b[p8], acc[p8][s], 0, 0, 0);
            }
#pragma unroll
            for (int p8 = 0; p8 < 8; p8++) {
                float bv = b3[(half * 8 + p8) * HDIM + n];
#pragma unroll
                for (int s = 0; s < 4; s++)
#pragma unroll
                    for (int i = 0; i < 4; i++)
                        mx[s][i] = fmaxf(mx[s][i], acc[p8][s][i] + bv);
            }
        }
#pragma unroll
        for (int s = 0; s < 4; s++)
#pragma unroll
            for (int i = 0; i < 4; i++)
                Outs[(s * 16 + q * 4 + i) * 456 + 224 + n] = f2bf(mx[s][i]);
    }
    __syncthreads();

    // ================= alpha = max_n([m1|m2] @ w4a.T + b4), K=448 =========
    {
        v4f acc = {0.f, 0.f, 0.f, 0.f};
        const int ar = (wave * 16 + col) * 456 + qo;
#pragma unroll
        for (int ks = 0; ks < 14; ks++) {
            v8bf a = *reinterpret_cast<const v8bf*>(&Outs[ar + ks * 32]);
            v8bf b = *reinterpret_cast<const v8bf*>(&w4[col * 456 + ks * 32 + qo]);
            acc = __builtin_amdgcn_mfma_f32_16x16x32_bf16(a, b, acc, 0, 0, 0);
        }
        float bb = b4[col];
        float v0 = acc[0] + bb, v1 = acc[1] + bb, v2 = acc[2] + bb, v3 = acc[3] + bb;
        for (int off = 1; off < 16; off <<= 1) {
            v0 = fmaxf(v0, __shfl_xor(v0, off, 16));
            v1 = fmaxf(v1, __shfl_xor(v1, off, 16));
            v2 = fmaxf(v2, __shfl_xor(v2, off, 16));
            v3 = fmaxf(v3, __shfl_xor(v3, off, 16));
        }
        if (col == 0) {
            const int tb = m0 + wave * 16 + q * 4;
            outv[tb + 0] = v0;
            outv[tb + 1] = v1;
            outv[tb + 2] = v2;
            outv[tb + 3] = v3;
        }
    }
}

// ---------------- argmax over T (block 0: ca -> ns, block 1: cb -> ne) ----
__global__ void k_argmax() {
    const float* src = blockIdx.x ? g_cb : g_ca;
    __shared__ float sv[256];
    __shared__ int si[256];
    float best = -INFINITY;
    int bi = T_LEN - 1;
    for (int t = threadIdx.x; t < T_LEN; t += 256) {
        float v = src[t];
        if (v > best) { best = v; bi = t; }
    }
    sv[threadIdx.x] = best; si[threadIdx.x] = bi;
    __syncthreads();
    for (int s = 128; s > 0; s >>= 1) {
        if (threadIdx.x < s) {
            float ov = sv[threadIdx.x + s]; int oi = si[threadIdx.x + s];
            if (ov > sv[threadIdx.x] || (ov == sv[threadIdx.x] && oi < si[threadIdx.x])) {
                sv[threadIdx.x] = ov; si[threadIdx.x] = oi;
            }
        }
        __syncthreads();
    }
    if (threadIdx.x == 0) g_ctrl[15 + blockIdx.x] = clampT(si[0]);
}

// ---------------- commit: freeze-select outputs + state, advance ctrl -----
__global__ void k_commit(int k, float* __restrict__ out) {
    int done = g_ctrl[k * 3 + 2];
    if (blockIdx.x < 128) {
        int is_beta = blockIdx.x >= 64;
        int t = ((int)blockIdx.x & 63) * 256 + threadIdx.x;
        float* row = out + (is_beta ? 4 * T_LEN : 0) + k * T_LEN;
        if (done) row[t] = row[t - T_LEN];
        else row[t] = (is_beta ? g_cb : g_ca)[t];
    } else {
        int t = threadIdx.x;
        if (t < HDIM && !done) { g_h[t] = g_ch[t]; g_c[t] = g_cc[t]; }
        if (t == 0) {
            int sp = g_ctrl[k * 3 + 0], ep = g_ctrl[k * 3 + 1];
            int ns = g_ctrl[15], ne = g_ctrl[16];
            if (done) {
                g_ctrl[(k + 1) * 3 + 0] = sp;
                g_ctrl[(k + 1) * 3 + 1] = ep;
                g_ctrl[(k + 1) * 3 + 2] = 1;
            } else {
                g_ctrl[(k + 1) * 3 + 0] = ns;
                g_ctrl[(k + 1) * 3 + 1] = ne;
                g_ctrl[(k + 1) * 3 + 2] = (k == 0) ? 0 : ((ns == sp && ne == ep) ? 1 : 0);
            }
        }
    }
}

extern "C" void kernel_launch(void* const* d_in, const int* in_sizes, int n_in,
                              void* d_out, int out_size, void* d_ws, size_t ws_size,
                              hipStream_t stream) {
    const float* U    = (const float*)d_in[0];
    const float* Wih  = (const float*)d_in[1];
    const float* Whh  = (const float*)d_in[2];
    const float* bih  = (const float*)d_in[3];
    const float* bhh  = (const float*)d_in[4];
    const float* s_w1 = (const float*)d_in[5];
    const float* s_w2 = (const float*)d_in[6];
    const float* s_b2 = (const float*)d_in[7];
    const float* s_w3 = (const float*)d_in[8];
    const float* s_b3 = (const float*)d_in[9];
    const float* s_w4 = (const float*)d_in[10];
    const float* s_b4 = (const float*)d_in[11];
    const float* e_w1 = (const float*)d_in[12];
    const float* e_w2 = (const float*)d_in[13];
    const float* e_b2 = (const float*)d_in[14];
    const float* e_w3 = (const float*)d_in[15];
    const float* e_b3 = (const float*)d_in[16];
    const float* e_w4 = (const float*)d_in[17];
    const float* e_b4 = (const float*)d_in[18];
    float* out = (float*)d_out;
    (void)d_ws; (void)ws_size; (void)in_sizes; (void)n_in; (void)out_size;

    unsigned short* w2s_d; unsigned short* w3s_d;
    hipGetSymbolAddress((void**)&w2s_d, HIP_SYMBOL(g_w2bf));
    hipGetSymbolAddress((void**)&w3s_d, HIP_SYMBOL(g_w3bf));
    unsigned short* w2e_d = w2s_d + 3200 * 416;
    unsigned short* w3e_d = w3s_d + 3200 * 224;

    // one-time (per call) conversions
    k_cvt_U<<<3200, 256, 0, stream>>>(U, T_LEN * 400 / 8);
    k_cvt_pad<<<650, 256, 0, stream>>>(s_w2, w2s_d, 3200, 600, 416, 400);
    k_cvt_pad<<<650, 256, 0, stream>>>(e_w2, w2e_d, 3200, 600, 416, 400);
    k_cvt_pad<<<350, 256, 0, stream>>>(s_w3, w3s_d, 3200, 200, 224, 200);
    k_cvt_pad<<<350, 256, 0, stream>>>(e_w3, w3e_d, 3200, 200, 224, 200);
    k_cvt_w4<<<57, 256, 0, stream>>>(s_w4, e_w4);

    k_init<<<1, 256, 0, stream>>>();
    for (int k = 0; k < 4; k++) {
        k_gates<<<50, 256, 0, stream>>>(U, Wih, Whh, bih, bhh, k);
        k_hc<<<1, 256, 0, stream>>>();
        k_r<<<25, 256, 0, stream>>>(U, s_w1, e_w1, k);
        k_rw2<<<400, 256, 0, stream>>>(s_w2, s_b2, e_w2, e_b2);
        k_fused<<<dim3(256, 2), 256, 0, stream>>>(s_b3, e_b3, s_b4, e_b4);
        k_argmax<<<2, 256, 0, stream>>>();
        k_commit<<<129, 256, 0, stream>>>(k, out);
    }
}

// Round 8
// 1929.372 us; speedup vs baseline: 1.4719x; 1.2914x over previous
//
#include <hip/hip_runtime.h>
#include <math.h>

#define T_LEN 16384
#define HDIM 200
#define NPOOL 16

typedef __bf16 v8bf __attribute__((ext_vector_type(8)));
typedef float v4f __attribute__((ext_vector_type(4)));

// ---- scratch in module-scope device globals: d_ws is never touched ----
__device__ float g_ca[T_LEN];
__device__ float g_cb[T_LEN];
__device__ float g_rw2s[NPOOL * HDIM];
__device__ float g_rw2e[NPOOL * HDIM];
__device__ float g_gates[4 * HDIM];
__device__ float g_h[HDIM];
__device__ float g_c[HDIM];
__device__ float g_ch[HDIM];
__device__ float g_cc[HDIM];
__device__ float g_rs[HDIM];
__device__ float g_re[HDIM];
__device__ int   g_ctrl[17];
// bf16 canonical staging (converted from f32 inputs each call)
__device__ __align__(16) unsigned short g_Ubf[T_LEN * 400];        // 13.1 MB
__device__ __align__(16) unsigned short g_w2bf[2][3200 * 416];     // cols 400..415 = 0
__device__ __align__(16) unsigned short g_w3bf[2][3200 * 224];     // cols 200..223 = 0
__device__ __align__(16) unsigned short g_w4bf[2][16 * 416];       // cols 400..415 = 0

__device__ inline unsigned short f2bf(float f) {
    unsigned int u = __builtin_bit_cast(unsigned int, f);
    unsigned int r = u + 0x7FFFu + ((u >> 16) & 1u);
    return (unsigned short)(r >> 16);
}
__device__ inline int clampT(int v) {
    return v < 0 ? 0 : (v >= T_LEN ? T_LEN - 1 : v);
}

// async global->LDS, 16B per lane; LDS dest = wave-uniform base + lane*16
__device__ inline void gl_lds16(const unsigned short* g, unsigned short* l) {
    __builtin_amdgcn_global_load_lds(
        (const __attribute__((address_space(1))) unsigned int*)g,
        (__attribute__((address_space(3))) unsigned int*)l,
        16, 0, 0);
}

// ---------------- merged f32->bf16 conversions + state init (1 launch) ----
#define CU_CH   819200            // U: 16384*400/8
#define C2_CH   166400            // w2: 3200*52
#define C3_CH   89600             // w3: 3200*28
#define C4_CH   832               // w4: 16*52
#define TOT_CH  (CU_CH + 2*C2_CH + 2*C3_CH + 2*C4_CH)

__device__ inline void cvt_chunk(const float* __restrict__ src, unsigned short* __restrict__ dst,
                                 int src_stride, int cpr, int ncc, int idx) {
    int r = idx / cpr, c = idx - r * cpr;
    unsigned short o[8] = {0, 0, 0, 0, 0, 0, 0, 0};
    if (c < ncc) {
        const float* s = src + r * src_stride + c * 8;
        float4 f0 = reinterpret_cast<const float4*>(s)[0];
        float4 f1 = reinterpret_cast<const float4*>(s)[1];
        o[0] = f2bf(f0.x); o[1] = f2bf(f0.y); o[2] = f2bf(f0.z); o[3] = f2bf(f0.w);
        o[4] = f2bf(f1.x); o[5] = f2bf(f1.y); o[6] = f2bf(f1.z); o[7] = f2bf(f1.w);
    }
    *reinterpret_cast<uint4*>(dst + r * (cpr * 8) + c * 8) = *reinterpret_cast<uint4*>(o);
}

__global__ void k_cvt_all(const float* __restrict__ U,
                          const float* __restrict__ s_w2, const float* __restrict__ e_w2,
                          const float* __restrict__ s_w3, const float* __restrict__ e_w3,
                          const float* __restrict__ s_w4, const float* __restrict__ e_w4) {
    int i = blockIdx.x * 256 + threadIdx.x;
    if (i < CU_CH) { cvt_chunk(U, g_Ubf, 400, 50, 50, i); return; }
    i -= CU_CH;
    if (i < C2_CH) { cvt_chunk(s_w2, g_w2bf[0], 600, 52, 50, i); return; }
    i -= C2_CH;
    if (i < C2_CH) { cvt_chunk(e_w2, g_w2bf[1], 600, 52, 50, i); return; }
    i -= C2_CH;
    if (i < C3_CH) { cvt_chunk(s_w3, g_w3bf[0], 200, 28, 25, i); return; }
    i -= C3_CH;
    if (i < C3_CH) { cvt_chunk(e_w3, g_w3bf[1], 200, 28, 25, i); return; }
    i -= C3_CH;
    if (i < C4_CH) { cvt_chunk(s_w4, g_w4bf[0], 400, 52, 50, i); return; }
    i -= C4_CH;
    if (i < C4_CH) { cvt_chunk(e_w4, g_w4bf[1], 400, 52, 50, i); return; }
    i -= C4_CH;
    if (i < HDIM) { g_h[i] = 0.f; g_c[i] = 0.f; return; }
    i -= HDIM;
    if (i == 0) { g_ctrl[0] = 0; g_ctrl[1] = 0; g_ctrl[2] = 0; }
}

// ---------------- gates = x@Wih.T + h@Whh.T + bih + bhh  (800 rows) -------
__global__ void k_gates(const float* __restrict__ U,
                        const float* __restrict__ Wih,
                        const float* __restrict__ Whh,
                        const float* __restrict__ bih,
                        const float* __restrict__ bhh,
                        int k) {
    int row = blockIdx.x * 16 + (threadIdx.x >> 4);
    int l = threadIdx.x & 15;
    int start = clampT(g_ctrl[k * 3 + 0]), end = clampT(g_ctrl[k * 3 + 1]);
    float sum = 0.f;
    for (int j = l; j < 800; j += 16) {
        float xv = (j < 400) ? U[start * 400 + j] : U[end * 400 + (j - 400)];
        sum += Wih[row * 800 + j] * xv;
    }
    for (int j = l; j < HDIM; j += 16)
        sum += Whh[row * HDIM + j] * g_h[j];
    for (int off = 8; off > 0; off >>= 1) sum += __shfl_xor(sum, off, 16);
    if (l == 0) g_gates[row] = sum + bih[row] + bhh[row];
}

// ---------------- LSTM cell update candidates -----------------------------
__global__ void k_hc() {
    int t = threadIdx.x;
    if (t < HDIM) {
        float gi = g_gates[t], gf = g_gates[HDIM + t];
        float gg = g_gates[2 * HDIM + t], go = g_gates[3 * HDIM + t];
        float si = 1.f / (1.f + expf(-gi));
        float sf = 1.f / (1.f + expf(-gf));
        float so = 1.f / (1.f + expf(-go));
        float tg = tanhf(gg);
        float cn = sf * g_c[t] + si * tg;
        g_cc[t] = cn;
        g_ch[t] = so * tanhf(cn);
    }
}

// ---------------- r = tanh([ch, U[s], U[e]] @ w1.T) for both nets ---------
__global__ void k_r(const float* __restrict__ U,
                    const float* __restrict__ s_w1,
                    const float* __restrict__ e_w1,
                    int k) {
    int g = blockIdx.x * 16 + (threadIdx.x >> 4);
    int l = threadIdx.x & 15;
    int net = g / HDIM, i = g % HDIM;
    const float* w1 = net ? e_w1 : s_w1;
    int start = clampT(g_ctrl[k * 3 + 0]), end = clampT(g_ctrl[k * 3 + 1]);
    float sum = 0.f;
    for (int j = l; j < 1000; j += 16) {
        float cv;
        if (j < 200) cv = g_ch[j];
        else if (j < 600) cv = U[start * 400 + (j - 200)];
        else cv = U[end * 400 + (j - 600)];
        sum += w1[i * 1000 + j] * cv;
    }
    for (int off = 8; off > 0; off >>= 1) sum += __shfl_xor(sum, off, 16);
    if (l == 0) { float* out = net ? g_re : g_rs; out[i] = tanhf(sum); }
}

// ---------------- rw2 = r @ w2[:,400:].T + b2  (3200 each net) ------------
__global__ void k_rw2(const float* __restrict__ s_w2,
                      const float* __restrict__ s_b2,
                      const float* __restrict__ e_w2,
                      const float* __restrict__ e_b2) {
    int g = blockIdx.x * 16 + (threadIdx.x >> 4);
    int l = threadIdx.x & 15;
    int net = g / 3200, n = g % 3200;
    const float* w2 = net ? e_w2 : s_w2;
    const float* b2 = net ? e_b2 : s_b2;
    const float* r = net ? g_re : g_rs;
    float sum = 0.f;
    for (int j = l; j < HDIM; j += 16)
        sum += w2[n * 600 + 400 + j] * r[j];
    for (int off = 8; off > 0; off >>= 1) sum += __shfl_xor(sum, off, 16);
    if (l == 0) { float* out = net ? g_rw2e : g_rw2s; out[n] = sum + b2[n]; }
}

// ---------------- fused HMN: B-in-LDS double-buffered tile pipeline -------
// grid 512 (1D, XCD-swizzled: net=(bid>>2)&1 so each XCD's L2 holds ONE
// net's weights). Block = 64 rows, 4 waves; wave owns rows wave*16..+15 and
// holds a1[13] in regs. All waves share a (jt,p) B-tile (16n x K) staged
// cooperatively via global_load_lds into frag-major LDS (call c at c*1024 +
// lane*16) -> hot ds_read_b128 lane-linear = conflict-free. Double buffer,
// ONE barrier per tile; stage(t+1) issued after barrier, overlaps compute(t).
// Tile t: [0,208) m1 (jt=t>>4, p=t&15), [208,416) m2 (13 jt x 16 p; R7 bug
// was T2=320 -> m2 n>=112 never computed).
// LDS: As 64x416 (53,248 B) + Bs 2x6656 shorts (26,624 B) = 79,872 B
// -> 2 blocks/CU, 8 waves/CU.
__global__ __launch_bounds__(256, 2) void k_fused(
    const float* __restrict__ b3s, const float* __restrict__ b3e,
    const float* __restrict__ b4s, const float* __restrict__ b4e) {
    const int bid = blockIdx.x;
    const int net = (bid >> 2) & 1;
    const int m0 = ((bid >> 3) * 4 + (bid & 3)) * 64;
    const unsigned short* w2 = g_w2bf[net];
    const unsigned short* w3 = g_w3bf[net];
    const unsigned short* w4 = g_w4bf[net];
    const float* b3 = net ? b3e : b3s;
    const float* b4 = net ? b4e : b4s;
    const float* rw2 = net ? g_rw2e : g_rw2s;
    float* outv = net ? g_cb : g_ca;
    __shared__ __align__(16) unsigned short As[64 * 416];
    __shared__ __align__(16) unsigned short Bs[2][6656];
    const int tid = threadIdx.x;
    // stage U rows into As (chunks 50,51 zeroed: K-tail must be finite 0s)
    for (int idx = tid; idx < 64 * 52; idx += 256) {
        int r = idx / 52, ch = idx - r * 52;
        uint4 v = make_uint4(0u, 0u, 0u, 0u);
        if (ch < 50) v = *reinterpret_cast<const uint4*>(g_Ubf + (m0 + r) * 400 + ch * 8);
        *reinterpret_cast<uint4*>(&As[r * 416 + ch * 8]) = v;
    }
    const int lane = tid & 63, wave = tid >> 6;
    const int q = lane >> 4, col = lane & 15;
    const int qo = q * 8;

    // a1 frags: A[m=col][k] of wave's rows, K=416 (cols 400..415 zero)
    __syncthreads();
    v8bf a1[13];
#pragma unroll
    for (int ks = 0; ks < 13; ks++)
        a1[ks] = *reinterpret_cast<const v8bf*>(&As[(wave * 16 + col) * 416 + ks * 32 + qo]);
    v8bf a2[7];

    const int T2 = 416;
    // prologue: stage tile 0 (m1 jt=0, p=0)
    {
        const unsigned short* gb = w2 + (0 * 200 + 0 + col) * 416 + qo;
        for (int c = wave; c < 13; c += 4) gl_lds16(gb + c * 32, &Bs[0][c * 512]);
    }
    v4f mx;
    for (int t = 0; t < T2; t++) {
        __syncthreads();  // drains own global_load_lds (vmcnt) + all waves' stage(t)
        // stage(t+1) into other buffer (its readers finished pre-barrier)
        if (t + 1 < T2) {
            int tn = t + 1;
            if (tn < 208) {
                int jtn = tn >> 4, pn = tn & 15;
                int j0n = (jtn < 12) ? jtn * 16 : 184;
                const unsigned short* gb = w2 + (pn * 200 + j0n + col) * 416 + qo;
                unsigned short* lb = Bs[tn & 1];
                for (int c = wave; c < 13; c += 4) gl_lds16(gb + c * 32, lb + c * 512);
            } else {
                int t2 = tn - 208;
                int jtn = t2 >> 4, pn = t2 & 15;
                int j0n = (jtn < 12) ? jtn * 16 : 184;
                const unsigned short* gb = w3 + (pn * 200 + j0n + col) * 224 + qo;
                unsigned short* lb = Bs[tn & 1];
                for (int c = wave; c < 7; c += 4) gl_lds16(gb + c * 32, lb + c * 512);
            }
        }
        if (t == 208) {
            // m1 done for own rows; load a2 (k 200..223 = stale-but-finite, w3 pad=0)
#pragma unroll
            for (int ks = 0; ks < 7; ks++)
                a2[ks] = *reinterpret_cast<const v8bf*>(&As[(wave * 16 + col) * 416 + ks * 32 + qo]);
        }
        const unsigned short* bb = Bs[t & 1];
        if (t < 208) {
            int jt = t >> 4, p = t & 15;
            int j0 = (jt < 12) ? jt * 16 : 184;
            int n = j0 + col;
            if (p == 0) mx = (v4f){-INFINITY, -INFINITY, -INFINITY, -INFINITY};
            v4f acc0 = {0.f, 0.f, 0.f, 0.f}, acc1 = {0.f, 0.f, 0.f, 0.f};
#pragma unroll
            for (int ks = 0; ks < 12; ks += 2) {
                v8bf b0 = *reinterpret_cast<const v8bf*>(&bb[ks * 512 + lane * 8]);
                acc0 = __builtin_amdgcn_mfma_f32_16x16x32_bf16(a1[ks], b0, acc0, 0, 0, 0);
                v8bf b1 = *reinterpret_cast<const v8bf*>(&bb[(ks + 1) * 512 + lane * 8]);
                acc1 = __builtin_amdgcn_mfma_f32_16x16x32_bf16(a1[ks + 1], b1, acc1, 0, 0, 0);
            }
            {
                v8bf b0 = *reinterpret_cast<const v8bf*>(&bb[12 * 512 + lane * 8]);
                acc0 = __builtin_amdgcn_mfma_f32_16x16x32_bf16(a1[12], b0, acc0, 0, 0, 0);
            }
            float rv = rw2[p * HDIM + n];
#pragma unroll
            for (int i = 0; i < 4; i++)
                mx[i] = fmaxf(mx[i], acc0[i] + acc1[i] + rv);
            if (p == 15) {
                int rb = (wave * 16 + q * 4) * 416 + n;
#pragma unroll
                for (int i = 0; i < 4; i++) As[rb + i * 416] = f2bf(mx[i]);
            }
        } else {
            int t2 = t - 208;
            int jt = t2 >> 4, p = t2 & 15;
            int j0 = (jt < 12) ? jt * 16 : 184;
            int n = j0 + col;
            if (p == 0) mx = (v4f){-INFINITY, -INFINITY, -INFINITY, -INFINITY};
            v4f acc0 = {0.f, 0.f, 0.f, 0.f}, acc1 = {0.f, 0.f, 0.f, 0.f};
#pragma unroll
            for (int ks = 0; ks < 6; ks += 2) {
                v8bf b0 = *reinterpret_cast<const v8bf*>(&bb[ks * 512 + lane * 8]);
                acc0 = __builtin_amdgcn_mfma_f32_16x16x32_bf16(a2[ks], b0, acc0, 0, 0, 0);
                v8bf b1 = *reinterpret_cast<const v8bf*>(&bb[(ks + 1) * 512 + lane * 8]);
                acc1 = __builtin_amdgcn_mfma_f32_16x16x32_bf16(a2[ks + 1], b1, acc1, 0, 0, 0);
            }
            {
                v8bf b0 = *reinterpret_cast<const v8bf*>(&bb[6 * 512 + lane * 8]);
                acc0 = __builtin_amdgcn_mfma_f32_16x16x32_bf16(a2[6], b0, acc0, 0, 0, 0);
            }
            float bv = b3[p * HDIM + n];
#pragma unroll
            for (int i = 0; i < 4; i++)
                mx[i] = fmaxf(mx[i], acc0[i] + acc1[i] + bv);
            if (p == 15) {
                int rb = (wave * 16 + q * 4) * 416 + 200 + n;
#pragma unroll
                for (int i = 0; i < 4; i++) As[rb + i * 416] = f2bf(mx[i]);
            }
        }
    }
    __syncthreads();  // all m1/m2 writes visible before alpha reads

    // alpha = max_n([m1|m2] @ w4.T + b4), K=416 (tail: a=0 x b=0)
    {
        v4f acc = {0.f, 0.f, 0.f, 0.f};
        const int ar = (wave * 16 + col) * 416;
#pragma unroll
        for (int ks = 0; ks < 13; ks++) {
            v8bf a = *reinterpret_cast<const v8bf*>(&As[ar + ks * 32 + qo]);
            v8bf b = *reinterpret_cast<const v8bf*>(&w4[col * 416 + ks * 32 + qo]);
            acc = __builtin_amdgcn_mfma_f32_16x16x32_bf16(a, b, acc, 0, 0, 0);
        }
        float bbi = b4[col];
        float v0 = acc[0] + bbi, v1 = acc[1] + bbi, v2 = acc[2] + bbi, v3 = acc[3] + bbi;
        for (int off = 1; off < 16; off <<= 1) {
            v0 = fmaxf(v0, __shfl_xor(v0, off, 16));
            v1 = fmaxf(v1, __shfl_xor(v1, off, 16));
            v2 = fmaxf(v2, __shfl_xor(v2, off, 16));
            v3 = fmaxf(v3, __shfl_xor(v3, off, 16));
        }
        if (col == 0) {
            const int tb = m0 + wave * 16 + q * 4;
            outv[tb + 0] = v0;
            outv[tb + 1] = v1;
            outv[tb + 2] = v2;
            outv[tb + 3] = v3;
        }
    }
}

// ---------------- argmax over T (block 0: ca -> ns, block 1: cb -> ne) ----
__global__ void k_argmax() {
    const float* src = blockIdx.x ? g_cb : g_ca;
    __shared__ float sv[256];
    __shared__ int si[256];
    float best = -INFINITY;
    int bi = T_LEN - 1;
    for (int t = threadIdx.x; t < T_LEN; t += 256) {
        float v = src[t];
        if (v > best) { best = v; bi = t; }
    }
    sv[threadIdx.x] = best; si[threadIdx.x] = bi;
    __syncthreads();
    for (int s = 128; s > 0; s >>= 1) {
        if (threadIdx.x < s) {
            float ov = sv[threadIdx.x + s]; int oi = si[threadIdx.x + s];
            if (ov > sv[threadIdx.x] || (ov == sv[threadIdx.x] && oi < si[threadIdx.x])) {
                sv[threadIdx.x] = ov; si[threadIdx.x] = oi;
            }
        }
        __syncthreads();
    }
    if (threadIdx.x == 0) g_ctrl[15 + blockIdx.x] = clampT(si[0]);
}

// ---------------- commit: freeze-select outputs + state, advance ctrl -----
__global__ void k_commit(int k, float* __restrict__ out) {
    int done = g_ctrl[k * 3 + 2];
    if (blockIdx.x < 128) {
        int is_beta = blockIdx.x >= 64;
        int t = ((int)blockIdx.x & 63) * 256 + threadIdx.x;
        float* row = out + (is_beta ? 4 * T_LEN : 0) + k * T_LEN;
        if (done) row[t] = row[t - T_LEN];
        else row[t] = (is_beta ? g_cb : g_ca)[t];
    } else {
        int t = threadIdx.x;
        if (t < HDIM && !done) { g_h[t] = g_ch[t]; g_c[t] = g_cc[t]; }
        if (t == 0) {
            int sp = g_ctrl[k * 3 + 0], ep = g_ctrl[k * 3 + 1];
            int ns = g_ctrl[15], ne = g_ctrl[16];
            if (done) {
                g_ctrl[(k + 1) * 3 + 0] = sp;
                g_ctrl[(k + 1) * 3 + 1] = ep;
                g_ctrl[(k + 1) * 3 + 2] = 1;
            } else {
                g_ctrl[(k + 1) * 3 + 0] = ns;
                g_ctrl[(k + 1) * 3 + 1] = ne;
                g_ctrl[(k + 1) * 3 + 2] = (k == 0) ? 0 : ((ns == sp && ne == ep) ? 1 : 0);
            }
        }
    }
}

extern "C" void kernel_launch(void* const* d_in, const int* in_sizes, int n_in,
                              void* d_out, int out_size, void* d_ws, size_t ws_size,
                              hipStream_t stream) {
    const float* U    = (const float*)d_in[0];
    const float* Wih  = (const float*)d_in[1];
    const float* Whh  = (const float*)d_in[2];
    const float* bih  = (const float*)d_in[3];
    const float* bhh  = (const float*)d_in[4];
    const float* s_w1 = (const float*)d_in[5];
    const float* s_w2 = (const float*)d_in[6];
    const float* s_b2 = (const float*)d_in[7];
    const float* s_w3 = (const float*)d_in[8];
    const float* s_b3 = (const float*)d_in[9];
    const float* s_w4 = (const float*)d_in[10];
    const float* s_b4 = (const float*)d_in[11];
    const float* e_w1 = (const float*)d_in[12];
    const float* e_w2 = (const float*)d_in[13];
    const float* e_b2 = (const float*)d_in[14];
    const float* e_w3 = (const float*)d_in[15];
    const float* e_b3 = (const float*)d_in[16];
    const float* e_w4 = (const float*)d_in[17];
    const float* e_b4 = (const float*)d_in[18];
    float* out = (float*)d_out;
    (void)d_ws; (void)ws_size; (void)in_sizes; (void)n_in; (void)out_size;

    const int cvt_blocks = (TOT_CH + HDIM + 1 + 255) / 256;
    k_cvt_all<<<cvt_blocks, 256, 0, stream>>>(U, s_w2, e_w2, s_w3, e_w3, s_w4, e_w4);

    for (int k = 0; k < 4; k++) {
        k_gates<<<50, 256, 0, stream>>>(U, Wih, Whh, bih, bhh, k);
        k_hc<<<1, 256, 0, stream>>>();
        k_r<<<25, 256, 0, stream>>>(U, s_w1, e_w1, k);
        k_rw2<<<400, 256, 0, stream>>>(s_w2, s_b2, e_w2, e_b2);
        k_fused<<<512, 256, 0, stream>>>(s_b3, e_b3, s_b4, e_b4);
        k_argmax<<<2, 256, 0, stream>>>();
        k_commit<<<129, 256, 0, stream>>>(k, out);
    }
}